// Round 1
// baseline (488.623 us; speedup 1.0000x reference)
//
#include <hip/hip_runtime.h>
#include <cstdint>
#include <cstddef>

#define NN 500000   // nodes
// IN_CH=64, HEADS=4, OUT_CH=32, F=128 out feats, GH=256 gate hidden, SEGS=1024

typedef __attribute__((ext_vector_type(8))) short short8;   // 8 bf16 (4 VGPRs) MFMA frag
typedef __attribute__((ext_vector_type(4))) float floatx4;  // MFMA accumulator

__device__ __forceinline__ unsigned short f2bf(float f) {
  union { float f; unsigned u; } v; v.f = f;
  unsigned r = v.u + 0x7FFFu + ((v.u >> 16) & 1u);  // RNE
  return (unsigned short)(r >> 16);
}

#define MFMA16(a, b, c) __builtin_amdgcn_mfma_f32_16x16x32_bf16((a), (b), (c), 0, 0, 0)

// ---------------------------------------------------------------------------
// Kernel W: convert fp32 weights -> bf16, pre-swizzled into MFMA A-fragment
// order: dst[((mtile*ksteps+ks)*64 + lane)*8 + j] = W[mtile*16+(lane&15)]
//                                                   [ks*32+(lane>>4)*8+j]
// so an A-frag load is one coalesced 16B global load per lane.
// ---------------------------------------------------------------------------
__global__ void swizzle_weights(const float* __restrict__ gw1, const float* __restrict__ gw2,
                                const float* __restrict__ mw1, const float* __restrict__ mw2,
                                unsigned short* __restrict__ gw1s, unsigned short* __restrict__ gw2s,
                                unsigned short* __restrict__ mw1s, unsigned short* __restrict__ mw2s) {
  int e = blockIdx.x * 256 + threadIdx.x;   // 45056 total
  const float* src; unsigned short* dst; int ksteps, rows, K, local;
  if (e < 16384)      { src = gw1; dst = gw1s; ksteps = 2; rows = 256; K = 64;  local = e; }
  else if (e < 20480) { src = gw2; dst = gw2s; ksteps = 8; rows = 4;   K = 256; local = e - 16384; }
  else if (e < 28672) { src = mw1; dst = mw1s; ksteps = 2; rows = 128; K = 64;  local = e - 20480; }
  else                { src = mw2; dst = mw2s; ksteps = 4; rows = 128; K = 128; local = e - 28672; }
  int j = local & 7, lane = (local >> 3) & 63, tile = local >> 9;
  int ks = tile % ksteps, mtile = tile / ksteps;
  int row = mtile * 16 + (lane & 15);
  int k   = ks * 32 + ((lane >> 4) & 3) * 8 + j;
  float v = (row < rows) ? src[row * K + k] : 0.0f;   // zero-pad (gw2: 4 rows -> 16)
  dst[local] = f2bf(v);
}

// ---------------------------------------------------------------------------
// Kernel B (gate): per 64-node chunk:
//   stage x -> LDS bf16; h = PReLU(gw1 * x^T) via MFMA (weights as A operand,
//   x^T as B operand -> C rows are weight-cols, contiguous per lane);
//   gate^T = gw2pad * h^T (K=256); escore = exp(gate) (no max needed, |g|<~2);
//   denom[seg][head] += escore via per-16-node-tile reduction (batch sorted).
// ---------------------------------------------------------------------------
__global__ __launch_bounds__(256) void gate_kernel(
    const float* __restrict__ x, const int* __restrict__ batch,
    const unsigned short* __restrict__ gw1s, const unsigned short* __restrict__ gw2s,
    const float* __restrict__ prelu_a,
    float* __restrict__ escore, float* __restrict__ denom) {
  __shared__ unsigned short xs[64 * 72];    // 64 nodes x 64 k, pad 72 (2-way free)
  __shared__ unsigned short hs[64 * 264];   // 64 nodes x 256, pad 264 (16B-aligned rows)
  int t = threadIdx.x;
  int base = blockIdx.x * 64;

  // stage x chunk -> bf16 LDS
#pragma unroll
  for (int i = 0; i < 4; ++i) {
    int idx = i * 1024 + t * 4;
    int node = idx >> 6, col = idx & 63;
    int gn = base + node;
    float4 v = make_float4(0.f, 0.f, 0.f, 0.f);
    if (gn < NN) v = *(const float4*)(x + (size_t)gn * 64 + col);
    uint2 p;
    p.x = (unsigned)f2bf(v.x) | ((unsigned)f2bf(v.y) << 16);
    p.y = (unsigned)f2bf(v.z) | ((unsigned)f2bf(v.w) << 16);
    *(uint2*)(xs + node * 72 + col) = p;
  }
  __syncthreads();

  int wave = t >> 6, lane = t & 63;
  int quad = lane >> 4, lcol = lane & 15;
  float slope = prelu_a[0];

  // x^T B-fragments: B[k][n=node] = x[node][k] -> row lcol, 8 contiguous k
  short8 bx[4][2];
#pragma unroll
  for (int nt = 0; nt < 4; ++nt)
#pragma unroll
    for (int ks = 0; ks < 2; ++ks)
      bx[nt][ks] = *(const short8*)(xs + (nt * 16 + lcol) * 72 + ks * 32 + quad * 8);

  // layer1: wave w computes h cols [w*64, w*64+64)
#pragma unroll
  for (int mt = 0; mt < 4; ++mt) {
    int gmt = wave * 4 + mt;
    short8 a0 = *(const short8*)(gw1s + ((size_t)(gmt * 2 + 0) * 64 + lane) * 8);
    short8 a1 = *(const short8*)(gw1s + ((size_t)(gmt * 2 + 1) * 64 + lane) * 8);
#pragma unroll
    for (int nt = 0; nt < 4; ++nt) {
      floatx4 c = {0.f, 0.f, 0.f, 0.f};
      c = MFMA16(a0, bx[nt][0], c);
      c = MFMA16(a1, bx[nt][1], c);
      unsigned short hh[4];
#pragma unroll
      for (int r = 0; r < 4; ++r) {
        float v = c[r];
        v = (v >= 0.f) ? v : slope * v;   // PReLU
        hh[r] = f2bf(v);
      }
      uint2 p; p.x = hh[0] | ((unsigned)hh[1] << 16); p.y = hh[2] | ((unsigned)hh[3] << 16);
      // lane holds node = nt*16+lcol, wcols gmt*16+quad*4 .. +3 (contiguous)
      *(uint2*)(hs + (nt * 16 + lcol) * 264 + gmt * 16 + quad * 4) = p;
    }
  }
  __syncthreads();

  // layer2: wave w owns node tile w; gate^T[head][node], K=256
  floatx4 c2 = {0.f, 0.f, 0.f, 0.f};
#pragma unroll
  for (int ks = 0; ks < 8; ++ks) {
    short8 a = *(const short8*)(gw2s + ((size_t)ks * 64 + lane) * 8);
    short8 b = *(const short8*)(hs + (wave * 16 + lcol) * 264 + ks * 32 + quad * 8);
    c2 = MFMA16(a, b, c2);
  }
  // quad 0 lanes hold heads 0..3 for node lcol
  int gn = base + wave * 16 + lcol;
  bool valid = gn < NN;
  float e0 = valid ? __expf(c2[0]) : 0.f;
  float e1 = valid ? __expf(c2[1]) : 0.f;
  float e2 = valid ? __expf(c2[2]) : 0.f;
  float e3 = valid ? __expf(c2[3]) : 0.f;
  if (quad == 0 && valid) {
    float4 st = make_float4(e0, e1, e2, e3);
    *(float4*)(escore + (size_t)gn * 4) = st;    // coalesced 16 lanes x 16B
  }
  int tb = base + wave * 16;
  int segFirst = batch[tb < NN ? tb : NN - 1];
  int tl = tb + 15;
  int segLast = batch[tl < NN ? tl : NN - 1];
  if (segFirst == segLast) {   // sorted => whole 16-node tile is one segment
    float s0 = e0, s1 = e1, s2 = e2, s3 = e3;
#pragma unroll
    for (int m = 1; m < 16; m <<= 1) {
      s0 += __shfl_xor(s0, m); s1 += __shfl_xor(s1, m);
      s2 += __shfl_xor(s2, m); s3 += __shfl_xor(s3, m);
    }
    if (lane == 0) {
      atomicAdd(&denom[segFirst * 4 + 0], s0);
      atomicAdd(&denom[segFirst * 4 + 1], s1);
      atomicAdd(&denom[segFirst * 4 + 2], s2);
      atomicAdd(&denom[segFirst * 4 + 3], s3);
    }
  } else if (quad == 0) {      // rare boundary tile: per-node atomics
    int seg = batch[gn < NN ? gn : NN - 1];
    atomicAdd(&denom[seg * 4 + 0], e0);
    atomicAdd(&denom[seg * 4 + 1], e1);
    atomicAdd(&denom[seg * 4 + 2], e2);
    atomicAdd(&denom[seg * 4 + 3], e3);
  }
}

// ---------------------------------------------------------------------------
// Kernel C (feat + pool): per 64-node chunk:
//   h1 = relu(mw1*x^T + b1) -> LDS; feat^T = mw2*h1^T + b2;
//   wave w owns fcols [32w,32w+32) -> exactly head w;
//   out[seg][fcol] += score*feat via shfl-reduce over node columns + atomics.
// ---------------------------------------------------------------------------
__global__ __launch_bounds__(256) void pool_kernel(
    const float* __restrict__ x, const int* __restrict__ batch,
    const unsigned short* __restrict__ mw1s, const unsigned short* __restrict__ mw2s,
    const float* __restrict__ b1, const float* __restrict__ b2,
    const float* __restrict__ escore, const float* __restrict__ denom,
    float* __restrict__ out) {
  __shared__ unsigned short xs[64 * 72];
  __shared__ unsigned short h1s[64 * 136];  // 64 x 128, pad 136
  __shared__ float score_s[256];            // [node64][head4]
  int t = threadIdx.x;
  int base = blockIdx.x * 64;

#pragma unroll
  for (int i = 0; i < 4; ++i) {
    int idx = i * 1024 + t * 4;
    int node = idx >> 6, col = idx & 63;
    int gn = base + node;
    float4 v = make_float4(0.f, 0.f, 0.f, 0.f);
    if (gn < NN) v = *(const float4*)(x + (size_t)gn * 64 + col);
    uint2 p;
    p.x = (unsigned)f2bf(v.x) | ((unsigned)f2bf(v.y) << 16);
    p.y = (unsigned)f2bf(v.z) | ((unsigned)f2bf(v.w) << 16);
    *(uint2*)(xs + node * 72 + col) = p;
  }
  {
    int gn = base + (t >> 2);
    float sc = 0.f;
    if (gn < NN) {
      float esc = escore[(size_t)base * 4 + t];         // coalesced
      int seg = batch[gn];
      sc = esc / (denom[seg * 4 + (t & 3)] + 1e-16f);
    }
    score_s[t] = sc;
  }
  __syncthreads();

  int wave = t >> 6, lane = t & 63;
  int quad = lane >> 4, lcol = lane & 15;

  short8 bx[4][2];
#pragma unroll
  for (int nt = 0; nt < 4; ++nt)
#pragma unroll
    for (int ks = 0; ks < 2; ++ks)
      bx[nt][ks] = *(const short8*)(xs + (nt * 16 + lcol) * 72 + ks * 32 + quad * 8);

  // MLP layer1: wave w -> wcols [w*32, w*32+32)
#pragma unroll
  for (int mt = 0; mt < 2; ++mt) {
    int gmt = wave * 2 + mt;
    short8 a0 = *(const short8*)(mw1s + ((size_t)(gmt * 2 + 0) * 64 + lane) * 8);
    short8 a1 = *(const short8*)(mw1s + ((size_t)(gmt * 2 + 1) * 64 + lane) * 8);
    float4 bias = *(const float4*)(b1 + gmt * 16 + quad * 4);
#pragma unroll
    for (int nt = 0; nt < 4; ++nt) {
      floatx4 c = {0.f, 0.f, 0.f, 0.f};
      c = MFMA16(a0, bx[nt][0], c);
      c = MFMA16(a1, bx[nt][1], c);
      unsigned short hh[4];
      float v0 = fmaxf(c[0] + bias.x, 0.f);
      float v1 = fmaxf(c[1] + bias.y, 0.f);
      float v2 = fmaxf(c[2] + bias.z, 0.f);
      float v3 = fmaxf(c[3] + bias.w, 0.f);
      hh[0] = f2bf(v0); hh[1] = f2bf(v1); hh[2] = f2bf(v2); hh[3] = f2bf(v3);
      uint2 p; p.x = hh[0] | ((unsigned)hh[1] << 16); p.y = hh[2] | ((unsigned)hh[3] << 16);
      *(uint2*)(h1s + (nt * 16 + lcol) * 136 + gmt * 16 + quad * 4) = p;
    }
  }
  __syncthreads();

  // MLP layer2 + weighted pooling
  short8 a2[2][4];
  float4 b2f[2];
#pragma unroll
  for (int mt = 0; mt < 2; ++mt) {
    int gmt = wave * 2 + mt;
#pragma unroll
    for (int ks = 0; ks < 4; ++ks)
      a2[mt][ks] = *(const short8*)(mw2s + ((size_t)(gmt * 4 + ks) * 64 + lane) * 8);
    b2f[mt] = *(const float4*)(b2 + gmt * 16 + quad * 4);
  }
  int lastIdx = (base + 63 < NN) ? base + 63 : NN - 1;
  int chunkUni = (batch[base] == batch[lastIdx]);
  int fcolBase0 = wave * 32 + quad * 4;            // mt=0 fcol of reg r: +r; mt=1: +16

  float acc[2][4] = {{0.f,0.f,0.f,0.f},{0.f,0.f,0.f,0.f}};
#pragma unroll
  for (int nt = 0; nt < 4; ++nt) {
    short8 bh[4];
#pragma unroll
    for (int ks = 0; ks < 4; ++ks)
      bh[ks] = *(const short8*)(h1s + (nt * 16 + lcol) * 136 + ks * 32 + quad * 8);
    float sc = score_s[(nt * 16 + lcol) * 4 + wave];   // head == wave
    float contrib[2][4];
#pragma unroll
    for (int mt = 0; mt < 2; ++mt) {
      floatx4 c = {0.f, 0.f, 0.f, 0.f};
#pragma unroll
      for (int ks = 0; ks < 4; ++ks) c = MFMA16(a2[mt][ks], bh[ks], c);
      contrib[mt][0] = sc * (c[0] + b2f[mt].x);
      contrib[mt][1] = sc * (c[1] + b2f[mt].y);
      contrib[mt][2] = sc * (c[2] + b2f[mt].z);
      contrib[mt][3] = sc * (c[3] + b2f[mt].w);
    }
    if (chunkUni) {
#pragma unroll
      for (int mt = 0; mt < 2; ++mt)
#pragma unroll
        for (int r = 0; r < 4; ++r) acc[mt][r] += contrib[mt][r];
    } else {
      int na = base + nt * 16, nb = na + 15;
      int segA = batch[na < NN ? na : NN - 1];
      int segB = batch[nb < NN ? nb : NN - 1];
      if (segA == segB) {
#pragma unroll
        for (int m = 1; m < 16; m <<= 1)
#pragma unroll
          for (int mt = 0; mt < 2; ++mt)
#pragma unroll
            for (int r = 0; r < 4; ++r)
              contrib[mt][r] += __shfl_xor(contrib[mt][r], m);
        if (lcol == 0)
#pragma unroll
          for (int mt = 0; mt < 2; ++mt)
#pragma unroll
            for (int r = 0; r < 4; ++r)
              atomicAdd(&out[segA * 128 + fcolBase0 + mt * 16 + r], contrib[mt][r]);
      } else {
        int gn = base + nt * 16 + lcol;
        int seg = batch[gn < NN ? gn : NN - 1];
#pragma unroll
        for (int mt = 0; mt < 2; ++mt)
#pragma unroll
          for (int r = 0; r < 4; ++r)
            atomicAdd(&out[seg * 128 + fcolBase0 + mt * 16 + r], contrib[mt][r]);
      }
    }
  }
  if (chunkUni) {
    int seg = batch[base];
#pragma unroll
    for (int m = 1; m < 16; m <<= 1)
#pragma unroll
      for (int mt = 0; mt < 2; ++mt)
#pragma unroll
        for (int r = 0; r < 4; ++r)
          acc[mt][r] += __shfl_xor(acc[mt][r], m);
    if (lcol == 0)
#pragma unroll
      for (int mt = 0; mt < 2; ++mt)
#pragma unroll
        for (int r = 0; r < 4; ++r)
          atomicAdd(&out[seg * 128 + fcolBase0 + mt * 16 + r], acc[mt][r]);
  }
}

// ---------------------------------------------------------------------------
extern "C" void kernel_launch(void* const* d_in, const int* in_sizes, int n_in,
                              void* d_out, int out_size, void* d_ws, size_t ws_size,
                              hipStream_t stream) {
  const float* x    = (const float*)d_in[0];
  const int*   batch = (const int*)d_in[1];
  // d_in[2] = num_segments (constant 1024, unused)
  const float* gw1 = (const float*)d_in[3];
  const float* pa  = (const float*)d_in[4];
  const float* gw2 = (const float*)d_in[5];
  const float* mw1 = (const float*)d_in[6];
  const float* mb1 = (const float*)d_in[7];
  const float* mw2 = (const float*)d_in[8];
  const float* mb2 = (const float*)d_in[9];
  float* out = (float*)d_out;

  char* ws = (char*)d_ws;
  float* escore = (float*)ws;                             // 500000*4 fp32 = 8,000,000 B
  float* denom  = (float*)(ws + 8000000);                 // 1024*4 fp32  = 16,384 B
  unsigned short* gw1s = (unsigned short*)(ws + 8016384); // 32,768 B
  unsigned short* gw2s = (unsigned short*)(ws + 8049152); // 8,192 B
  unsigned short* mw1s = (unsigned short*)(ws + 8057344); // 16,384 B
  unsigned short* mw2s = (unsigned short*)(ws + 8073728); // 32,768 B

  hipMemsetAsync(denom, 0, 4096 * sizeof(float), stream);
  hipMemsetAsync(out, 0, (size_t)out_size * sizeof(float), stream);

  swizzle_weights<<<176, 256, 0, stream>>>(gw1, gw2, mw1, mw2, gw1s, gw2s, mw1s, mw2s);

  int nblk = (NN + 63) / 64;   // 7813
  gate_kernel<<<nblk, 256, 0, stream>>>(x, batch, gw1s, gw2s, pa, escore, denom);
  pool_kernel<<<nblk, 256, 0, stream>>>(x, batch, mw1s, mw2s, mb1, mb2, escore, denom, out);
}